// Round 8
// baseline (281.033 us; speedup 1.0000x reference)
//
#include <hip/hip_runtime.h>

typedef __attribute__((ext_vector_type(8))) short bf16x8;
typedef __attribute__((ext_vector_type(4))) float f32x4;

static __device__ __forceinline__ unsigned short f2bf(float f) {
    unsigned int u = __float_as_uint(f);
    u += 0x7fffu + ((u >> 16) & 1u);
    return (unsigned short)(u >> 16);
}
// round-half-up: P-values only (|rel err| <= 2^-9, tolerance-safe)
static __device__ __forceinline__ unsigned int pack2bf(float lo, float hi) {
    return ((__float_as_uint(lo) + 0x8000u) >> 16) |
           ((__float_as_uint(hi) + 0x8000u) & 0xffff0000u);
}
static __device__ __forceinline__ float bf2f(short v) {
    return __uint_as_float(((unsigned int)(unsigned short)v) << 16);
}
static __device__ __forceinline__ bf16x8 cvt8v(const float* p) {
    f32x4 a = *(const f32x4*)p, b = *(const f32x4*)(p + 4);
    bf16x8 r;
    r[0] = (short)f2bf(a[0]); r[1] = (short)f2bf(a[1]);
    r[2] = (short)f2bf(a[2]); r[3] = (short)f2bf(a[3]);
    r[4] = (short)f2bf(b[0]); r[5] = (short)f2bf(b[1]);
    r[6] = (short)f2bf(b[2]); r[7] = (short)f2bf(b[3]);
    return r;
}
static __device__ __forceinline__ bf16x8 scale8v(bf16x8 v, float s) {
    bf16x8 r;
    #pragma unroll
    for (int j = 0; j < 8; ++j) r[j] = (short)f2bf(bf2f(v[j]) * s);
    return r;
}
static __device__ __forceinline__ uint4 cvt8(const float* p) {
    bf16x8 r = cvt8v(p);
    union { bf16x8 v; uint4 u; } c; c.v = r; return c.u;
}
// async global->LDS, 16B/lane; LDS dest = wave-uniform base + lane*16
static __device__ __forceinline__ void glds16(const unsigned short* g, unsigned short* l) {
    __builtin_amdgcn_global_load_lds(
        (const __attribute__((address_space(1))) unsigned int*)g,
        (__attribute__((address_space(3))) unsigned int*)l, 16, 0, 0);
}

// ---------------------------------------------------------------------------
// Fused prep: cvt x -> x_bf, cvt k_g -> kg_bf, transpose+cvt W_qkv, W_out.
// grid 5120: [0,2048) x | [2048,4096) k_g | [4096,4864) Wqkv | [4864,5120) Wout
// ---------------------------------------------------------------------------
static __device__ __forceinline__ void transpose_tile(
    const float* __restrict__ src, unsigned short* __restrict__ dst,
    int R, int C, int bx, int by, int tid)
{
    __shared__ unsigned short t[64 * 72];
    const int r0 = by * 64, c0 = bx * 64;
    #pragma unroll
    for (int i = 0; i < 4; ++i) {
        int idx = tid + i * 256;
        int row = idx >> 4, seg = idx & 15;
        f32x4 v = *(const f32x4*)&src[(size_t)(r0 + row) * C + c0 + seg * 4];
        #pragma unroll
        for (int j = 0; j < 4; ++j) t[row * 72 + seg * 4 + j] = f2bf(v[j]);
    }
    __syncthreads();
    #pragma unroll
    for (int i = 0; i < 2; ++i) {
        int idx = tid + i * 256;
        int row = idx >> 3, seg = idx & 7;
        uint4 tv; unsigned short* tmp = (unsigned short*)&tv;
        #pragma unroll
        for (int j = 0; j < 8; ++j) tmp[j] = t[(seg * 8 + j) * 72 + row];
        *(uint4*)&dst[(size_t)(c0 + row) * R + r0 + seg * 8] = tv;
    }
}

__global__ __launch_bounds__(256) void prep_all(
    const float* __restrict__ x, unsigned short* __restrict__ x_bf,
    const float* __restrict__ kg, unsigned short* __restrict__ kg_bf,
    const float* __restrict__ Wq, unsigned short* __restrict__ wtq,
    const float* __restrict__ Wo, unsigned short* __restrict__ wto)
{
    const int t = blockIdx.x, tid = threadIdx.x;
    if (t < 2048) {
        size_t j = ((size_t)t * 256 + tid) * 8;
        *(uint4*)&x_bf[j] = cvt8(&x[j]);
    } else if (t < 4096) {
        size_t j = ((size_t)(t - 2048) * 256 + tid) * 8;
        *(uint4*)&kg_bf[j] = cvt8(&kg[j]);
    } else if (t < 4864) {
        int tt = t - 4096;               // W_qkv [1024][3072]: 48 col-tiles x 16
        transpose_tile(Wq, wtq, 1024, 3072, tt % 48, tt / 48, tid);
    } else {
        int tt = t - 4864;               // W_out [1024][1024]
        transpose_tile(Wo, wto, 1024, 1024, tt & 15, tt >> 4, tid);
    }
}

// ---------------------------------------------------------------------------
// gemm_qkv: qkv = x_bf @ wtq^T.  Q,K cols (bx<16) -> qk[4096][2048].
// V cols (bx>=16) -> written TRANSPOSED to vt[bh][hd=64][L=2048] via LDS.
// 128x128 tile, BK=32, glds16 staging (m97 pattern).  R0-exact.
// ---------------------------------------------------------------------------
__global__ __launch_bounds__(256) void gemm_qkv(
    const unsigned short* __restrict__ A, const unsigned short* __restrict__ Bt,
    unsigned short* __restrict__ qk, unsigned short* __restrict__ vt)
{
    const int K = 1024;
    __shared__ unsigned short As[128 * 32];
    __shared__ unsigned short Bs[128 * 32];
    __shared__ unsigned short Tb[128 * 136];   // V-transpose scratch
    const int tid = threadIdx.x;
    const int wave = tid >> 6, lane = tid & 63, quad = lane >> 4, l16 = lane & 15;
    const int wr = (wave >> 1) * 64, wc = (wave & 1) * 64;
    const int m0 = blockIdx.y * 128, n0 = blockIdx.x * 128;

    const unsigned short* ga = A  + (size_t)(m0 + wave * 32 + (lane >> 2)) * K + (lane & 3) * 8;
    const unsigned short* gb = Bt + (size_t)(n0 + wave * 32 + (lane >> 2)) * K + (lane & 3) * 8;
    unsigned short* la = &As[wave * 32 * 32];
    unsigned short* lb = &Bs[wave * 32 * 32];
    const size_t step16 = (size_t)16 * K;

    f32x4 acc[4][4];
    #pragma unroll
    for (int i = 0; i < 4; ++i)
        #pragma unroll
        for (int j = 0; j < 4; ++j) acc[i][j] = (f32x4){0.f, 0.f, 0.f, 0.f};

    for (int kt = 0; kt < K; kt += 32) {
        glds16(ga, la); glds16(ga + step16, la + 512);
        glds16(gb, lb); glds16(gb + step16, lb + 512);
        ga += 32; gb += 32;
        __syncthreads();
        bf16x8 af[4], bf[4];
        #pragma unroll
        for (int i = 0; i < 4; ++i) {
            af[i] = *(const bf16x8*)&As[(wr + i * 16 + l16) * 32 + quad * 8];
            bf[i] = *(const bf16x8*)&Bs[(wc + i * 16 + l16) * 32 + quad * 8];
        }
        #pragma unroll
        for (int mi = 0; mi < 4; ++mi)
            #pragma unroll
            for (int ni = 0; ni < 4; ++ni)
                acc[mi][ni] = __builtin_amdgcn_mfma_f32_16x16x32_bf16(
                    af[mi], bf[ni], acc[mi][ni], 0, 0, 0);
        __syncthreads();
    }

    if (blockIdx.x < 16) {        // Q|K part: normal write, stride 2048
        #pragma unroll
        for (int mi = 0; mi < 4; ++mi)
            #pragma unroll
            for (int ni = 0; ni < 4; ++ni)
                #pragma unroll
                for (int r = 0; r < 4; ++r) {
                    int row = m0 + wr + mi * 16 + quad * 4 + r;
                    int col = n0 + wc + ni * 16 + l16;
                    qk[(size_t)row * 2048 + col] = f2bf(acc[mi][ni][r]);
                }
    } else {                      // V part: transpose via LDS -> vt[bh][hd][L]
        __syncthreads();
        #pragma unroll
        for (int mi = 0; mi < 4; ++mi)
            #pragma unroll
            for (int ni = 0; ni < 4; ++ni)
                #pragma unroll
                for (int r = 0; r < 4; ++r) {
                    int col = wc + ni * 16 + l16;            // hd-ish (0..127)
                    int row = wr + mi * 16 + quad * 4 + r;   // pos (0..127)
                    Tb[col * 136 + row] = f2bf(acc[mi][ni][r]);
                }
        __syncthreads();
        const int col = tid >> 1, r0 = (tid & 1) * 64;
        const int bh = (m0 >> 11) * 16 + ((int)blockIdx.x - 16) * 2 + (col >> 6);
        size_t base = ((size_t)bh * 64 + (col & 63)) * 2048 + (m0 & 2047) + r0;
        #pragma unroll
        for (int k = 0; k < 8; ++k)
            *(uint4*)&vt[base + k * 8] = *(const uint4*)&Tb[col * 136 + r0 + k * 8];
    }
}

// ---------------------------------------------------------------------------
// gemm2: out = y_ws @ wto^T, f32 out.  128(M) x 64(N) tile -> 512 blocks.
// 4 waves: 2x2, each 64x32.  R0-exact.
// ---------------------------------------------------------------------------
__global__ __launch_bounds__(256) void gemm_n64(
    const unsigned short* __restrict__ A, const unsigned short* __restrict__ Bt,
    float* __restrict__ C)
{
    const int K = 1024, N = 1024;
    __shared__ unsigned short As[128 * 32];
    __shared__ unsigned short Bs[64 * 32];
    const int tid = threadIdx.x;
    const int wave = tid >> 6, lane = tid & 63, quad = lane >> 4, l16 = lane & 15;
    const int wr = (wave >> 1) * 64, wc = (wave & 1) * 32;
    const int m0 = blockIdx.y * 128, n0 = blockIdx.x * 64;

    const unsigned short* ga = A  + (size_t)(m0 + wave * 32 + (lane >> 2)) * K + (lane & 3) * 8;
    const unsigned short* gb = Bt + (size_t)(n0 + wave * 16 + (lane >> 2)) * K + (lane & 3) * 8;
    unsigned short* la = &As[wave * 32 * 32];
    unsigned short* lb = &Bs[wave * 16 * 32];
    const size_t step16 = (size_t)16 * K;

    f32x4 acc[4][2];
    #pragma unroll
    for (int i = 0; i < 4; ++i)
        #pragma unroll
        for (int j = 0; j < 2; ++j) acc[i][j] = (f32x4){0.f, 0.f, 0.f, 0.f};

    for (int kt = 0; kt < K; kt += 32) {
        glds16(ga, la); glds16(ga + step16, la + 512);
        glds16(gb, lb);
        ga += 32; gb += 32;
        __syncthreads();
        bf16x8 af[4], bf[2];
        #pragma unroll
        for (int i = 0; i < 4; ++i)
            af[i] = *(const bf16x8*)&As[(wr + i * 16 + l16) * 32 + quad * 8];
        #pragma unroll
        for (int i = 0; i < 2; ++i)
            bf[i] = *(const bf16x8*)&Bs[(wc + i * 16 + l16) * 32 + quad * 8];
        #pragma unroll
        for (int mi = 0; mi < 4; ++mi)
            #pragma unroll
            for (int ni = 0; ni < 2; ++ni)
                acc[mi][ni] = __builtin_amdgcn_mfma_f32_16x16x32_bf16(
                    af[mi], bf[ni], acc[mi][ni], 0, 0, 0);
        __syncthreads();
    }
    #pragma unroll
    for (int mi = 0; mi < 4; ++mi)
        #pragma unroll
        for (int ni = 0; ni < 2; ++ni)
            #pragma unroll
            for (int r = 0; r < 4; ++r) {
                int row = m0 + wr + mi * 16 + quad * 4 + r;
                int col = n0 + wc + ni * 16 + l16;
                C[(size_t)row * N + col] = acc[mi][ni][r];
            }
}

// ---------------------------------------------------------------------------
// attn12 = attn7 + T14 async-STAGE split (learn_hip m214 r277: +17% attn).
// Identical LDS (32 KiB, 5 blk/CU), grid, swizzles, compute, and staged
// bytes as attn7.  ONLY the staging schedule changes: tile t+1 is loaded
// into 6 uint4 REGISTERS during tile t's compute (issue-early), and written
// to LDS with ds_write_b128 after the tile-boundary barrier (write-late).
// Both barriers now drain near-empty vmem queues instead of exposing the
// full HBM/L2 latency of just-issued global_load_lds every tile.
// ---------------------------------------------------------------------------
__global__ __launch_bounds__(256, 5) void attn12(
    const unsigned short* __restrict__ qk, const float* __restrict__ qg,
    const unsigned short* __restrict__ kgb, const unsigned short* __restrict__ vt,
    unsigned short* __restrict__ y)
{
    const int L = 2048, DS = 2048, Dm = 1024;
    const float SC2 = 0.125f * 1.44269504088896f / 7.6246189861593985f;

    const int qt = 31 - (int)blockIdx.y;   // heavy tiles dispatch first
    const int bh = blockIdx.x, b = bh >> 4, h = bh & 15;
    const int tid = threadIdx.x, wave = tid >> 6, lane = tid & 63;
    const int quad = lane >> 4, l16 = lane & 15;

    __shared__ unsigned short K_l[4096];     // [64][64] swizzled
    __shared__ unsigned short G_l[4096];
    __shared__ unsigned short V_l[4096];     // [hd][key] swizzled
    __shared__ unsigned short P_l[4096];     // per-wave [16][64] swizzled
    unsigned short* Pw = &P_l[wave * 1024];

    bf16x8 qf[2], gf[2];
    {
        const int qrow = qt * 64 + wave * 16 + l16;
        const unsigned short* qp = qk + (size_t)(b * L + qrow) * DS + h * 64;
        const float* gp = qg + (size_t)(b * L + qrow) * Dm + h * 64;
        #pragma unroll
        for (int c = 0; c < 2; ++c) {
            qf[c] = scale8v(*(const bf16x8*)(qp + c * 32 + quad * 8), SC2);
            gf[c] = scale8v(cvt8v(gp + c * 32 + quad * 8), SC2);
        }
    }

    f32x4 o[4];
    #pragma unroll
    for (int nd = 0; nd < 4; ++nd) o[nd] = (f32x4){0.f, 0.f, 0.f, 0.f};
    float lsum = 0.f;

    // per-lane global sources (identical to attn7's glds16 sources)
    const int srow = wave * 16 + (lane >> 3);
    const int c8 = (((lane & 7) ^ (lane >> 3)) & 7) * 8;
    const unsigned short* pk = qk + (size_t)(b * L + srow) * DS + 1024 + h * 64 + c8;
    const unsigned short* pg = kgb + (size_t)(b * L + srow) * Dm + h * 64 + c8;
    const unsigned short* pv = vt + ((size_t)bh * 64 + srow) * L + c8;
    unsigned short* lK = &K_l[wave * 1024];
    unsigned short* lG = &G_l[wave * 1024];
    unsigned short* lV = &V_l[wave * 1024];

    // T14 prefetch registers (6 x uint4 = 24 VGPR; total ~76, still 5 blk/CU)
    uint4 rK0, rK1, rG0, rG1, rV0, rV1;
    auto LOADT = [&]() {            // issue-early: global -> regs, no wait
        rK0 = *(const uint4*)pk;  rK1 = *(const uint4*)(pk + 8 * DS);
        rG0 = *(const uint4*)pg;  rG1 = *(const uint4*)(pg + 8 * Dm);
        rV0 = *(const uint4*)pv;  rV1 = *(const uint4*)(pv + 8 * L);
        pk += 64 * DS; pg += 64 * Dm; pv += 64;
    };
    auto WRITET = [&]() {           // write-late: regs -> LDS (same bytes/dest
        *(uint4*)&lK[lane * 8] = rK0;   //  layout as glds16: base + lane*16B)
        *(uint4*)&lK[512 + lane * 8] = rK1;
        *(uint4*)&lG[lane * 8] = rG0;
        *(uint4*)&lG[512 + lane * 8] = rG1;
        *(uint4*)&lV[lane * 8] = rV0;
        *(uint4*)&lV[512 + lane * 8] = rV1;
    };

    const int rb = l16 * 128;
    const int swz0 = ((quad     ^ (l16 & 7)) * 16);
    const int swz1 = (((4 + quad) ^ (l16 & 7)) * 16);
    // P write: short idx l16*64 + ((ni*2+(quad>>1))^(l16&7))*8 + (quad&1)*4
    const int pwb = l16 * 64 + (quad & 1) * 4;
    const int pwc = quad >> 1, pxr = l16 & 7;

    LOADT();                        // prologue: tile 0 -> regs

    for (int kt = 0; kt < qt; ++kt) {
        __syncthreads();            // all waves done reading previous tile
        WRITET();                   // reg-dep vmcnt wait: loads are ~landed
        __syncthreads();            // staged tile visible to all waves
        LOADT();                    // prefetch tile kt+1 (kt+1 <= qt = diag)

        #pragma unroll
        for (int ni = 0; ni < 4; ++ni) {
            bf16x8 kf0 = *(const bf16x8*)((const char*)K_l + rb + swz0 + ni * 2048);
            bf16x8 kf1 = *(const bf16x8*)((const char*)K_l + rb + swz1 + ni * 2048);
            bf16x8 gb0 = *(const bf16x8*)((const char*)G_l + rb + swz0 + ni * 2048);
            bf16x8 gb1 = *(const bf16x8*)((const char*)G_l + rb + swz1 + ni * 2048);
            f32x4 a = (f32x4){0.f, 0.f, 0.f, 0.f};
            a = __builtin_amdgcn_mfma_f32_16x16x32_bf16(kf0, qf[0], a, 0, 0, 0);
            a = __builtin_amdgcn_mfma_f32_16x16x32_bf16(gb0, gf[0], a, 0, 0, 0);
            a = __builtin_amdgcn_mfma_f32_16x16x32_bf16(kf1, qf[1], a, 0, 0, 0);
            a = __builtin_amdgcn_mfma_f32_16x16x32_bf16(gb1, gf[1], a, 0, 0, 0);
            float e0 = exp2f(a[0]), e1 = exp2f(a[1]);
            float e2 = exp2f(a[2]), e3 = exp2f(a[3]);
            lsum += (e0 + e1) + (e2 + e3);
            unsigned int p01 = pack2bf(e0, e1), p23 = pack2bf(e2, e3);
            *(unsigned long long*)&Pw[pwb + (((ni * 2 + pwc) ^ pxr) * 8)] =
                ((unsigned long long)p23 << 32) | p01;
        }
        asm volatile("s_waitcnt lgkmcnt(0)" ::: "memory");

        bf16x8 pa[2];
        #pragma unroll
        for (int c = 0; c < 2; ++c)
            pa[c] = *(const bf16x8*)&Pw[l16 * 64 + (((c * 4 + quad) ^ pxr) * 8)];
        #pragma unroll
        for (int nd = 0; nd < 4; ++nd) {
            bf16x8 vf0 = *(const bf16x8*)((const char*)V_l + rb + swz0 + nd * 2048);
            bf16x8 vf1 = *(const bf16x8*)((const char*)V_l + rb + swz1 + nd * 2048);
            o[nd] = __builtin_amdgcn_mfma_f32_16x16x32_bf16(pa[0], vf0, o[nd], 0, 0, 0);
            o[nd] = __builtin_amdgcn_mfma_f32_16x16x32_bf16(pa[1], vf1, o[nd], 0, 0, 0);
        }
    }

    // ---- diagonal tile kt == qt (already in regs from last LOADT) ----
    {
        __syncthreads();
        WRITET();
        __syncthreads();

        #pragma unroll
        for (int ni = 0; ni < 4; ++ni) {
            if (ni > wave) {
                *(unsigned long long*)&Pw[pwb + (((ni * 2 + pwc) ^ pxr) * 8)] = 0ull;
                continue;
            }
            bf16x8 kf0 = *(const bf16x8*)((const char*)K_l + rb + swz0 + ni * 2048);
            bf16x8 kf1 = *(const bf16x8*)((const char*)K_l + rb + swz1 + ni * 2048);
            bf16x8 gb0 = *(const bf16x8*)((const char*)G_l + rb + swz0 + ni * 2048);
            bf16x8 gb1 = *(const bf16x8*)((const char*)G_l + rb + swz1 + ni * 2048);
            f32x4 a = (f32x4){0.f, 0.f, 0.f, 0.f};
            a = __builtin_amdgcn_mfma_f32_16x16x32_bf16(kf0, qf[0], a, 0, 0, 0);
            a = __builtin_amdgcn_mfma_f32_16x16x32_bf16(gb0, gf[0], a, 0, 0, 0);
            a = __builtin_amdgcn_mfma_f32_16x16x32_bf16(kf1, qf[1], a, 0, 0, 0);
            a = __builtin_amdgcn_mfma_f32_16x16x32_bf16(gb1, gf[1], a, 0, 0, 0);
            float e0, e1, e2, e3;
            if (ni < wave) {
                e0 = exp2f(a[0]); e1 = exp2f(a[1]);
                e2 = exp2f(a[2]); e3 = exp2f(a[3]);
            } else {
                e0 = (quad * 4 + 0 <= l16) ? exp2f(a[0]) : 0.f;
                e1 = (quad * 4 + 1 <= l16) ? exp2f(a[1]) : 0.f;
                e2 = (quad * 4 + 2 <= l16) ? exp2f(a[2]) : 0.f;
                e3 = (quad * 4 + 3 <= l16) ? exp2f(a[3]) : 0.f;
            }
            lsum += (e0 + e1) + (e2 + e3);
            unsigned int p01 = pack2bf(e0, e1), p23 = pack2bf(e2, e3);
            *(unsigned long long*)&Pw[pwb + (((ni * 2 + pwc) ^ pxr) * 8)] =
                ((unsigned long long)p23 << 32) | p01;
        }
        asm volatile("s_waitcnt lgkmcnt(0)" ::: "memory");

        bf16x8 pa[2];
        #pragma unroll
        for (int c = 0; c < 2; ++c)
            pa[c] = *(const bf16x8*)&Pw[l16 * 64 + (((c * 4 + quad) ^ pxr) * 8)];
        #pragma unroll
        for (int nd = 0; nd < 4; ++nd) {
            bf16x8 vf0 = *(const bf16x8*)((const char*)V_l + rb + swz0 + nd * 2048);
            bf16x8 vf1 = *(const bf16x8*)((const char*)V_l + rb + swz1 + nd * 2048);
            o[nd] = __builtin_amdgcn_mfma_f32_16x16x32_bf16(pa[0], vf0, o[nd], 0, 0, 0);
            o[nd] = __builtin_amdgcn_mfma_f32_16x16x32_bf16(pa[1], vf1, o[nd], 0, 0, 0);
        }
    }

    float rs = lsum;
    rs += __shfl_xor(rs, 16);
    rs += __shfl_xor(rs, 32);
    #pragma unroll
    for (int r = 0; r < 4; ++r) {
        float inv = 1.f / __shfl(rs, (lane & 48) | (quad * 4 + r));
        int row = qt * 64 + wave * 16 + quad * 4 + r;
        #pragma unroll
        for (int nd = 0; nd < 4; ++nd)
            y[(size_t)(b * L + row) * Dm + h * 64 + nd * 16 + l16] =
                f2bf(o[nd][r] * inv);
    }
}

// ---------------------------------------------------------------------------
extern "C" void kernel_launch(void* const* d_in, const int* in_sizes, int n_in,
                              void* d_out, int out_size, void* d_ws, size_t ws_size,
                              hipStream_t stream) {
    const float* x     = (const float*)d_in[0];
    const float* q_g   = (const float*)d_in[1];
    const float* k_g   = (const float*)d_in[2];
    const float* W_qkv = (const float*)d_in[3];
    const float* W_out = (const float*)d_in[4];
    float* out = (float*)d_out;
    unsigned short* ws = (unsigned short*)d_ws;

    unsigned short* qk_ws = ws;                  // [4096][2048]  Q|K
    unsigned short* y_ws  = ws + 8388608;        // [4096][1024]
    unsigned short* wtq   = ws + 12582912;       // [3072][1024]
    unsigned short* wto   = ws + 15728640;       // [1024][1024]
    unsigned short* kg_bf = ws + 16777216;       // [4096][1024]
    unsigned short* x_bf  = ws + 20971520;       // [4096][1024]
    unsigned short* vt_bf = ws + 25165824;       // [32][64][2048]

    dim3 blk(256);
    prep_all<<<5120, blk, 0, stream>>>(x, x_bf, k_g, kg_bf, W_qkv, wtq, W_out, wto);
    gemm_qkv<<<dim3(24, 32), blk, 0, stream>>>(x_bf, wtq, qk_ws, vt_bf);
    attn12<<<dim3(32, 32), blk, 0, stream>>>(qk_ws, q_g, kg_bf, vt_bf, y_ws);
    gemm_n64<<<dim3(16, 32), blk, 0, stream>>>(y_ws, wto, out);
}

// Round 9
// 226.981 us; speedup vs baseline: 1.2381x; 1.2381x over previous
//
#include <hip/hip_runtime.h>

typedef __attribute__((ext_vector_type(8))) short bf16x8;
typedef __attribute__((ext_vector_type(4))) float f32x4;

static __device__ __forceinline__ unsigned short f2bf(float f) {
    unsigned int u = __float_as_uint(f);
    u += 0x7fffu + ((u >> 16) & 1u);
    return (unsigned short)(u >> 16);
}
// round-half-up: P-values only (|rel err| <= 2^-9, tolerance-safe)
static __device__ __forceinline__ unsigned int pack2bf(float lo, float hi) {
    return ((__float_as_uint(lo) + 0x8000u) >> 16) |
           ((__float_as_uint(hi) + 0x8000u) & 0xffff0000u);
}
static __device__ __forceinline__ float bf2f(short v) {
    return __uint_as_float(((unsigned int)(unsigned short)v) << 16);
}
static __device__ __forceinline__ bf16x8 cvt8v(const float* p) {
    f32x4 a = *(const f32x4*)p, b = *(const f32x4*)(p + 4);
    bf16x8 r;
    r[0] = (short)f2bf(a[0]); r[1] = (short)f2bf(a[1]);
    r[2] = (short)f2bf(a[2]); r[3] = (short)f2bf(a[3]);
    r[4] = (short)f2bf(b[0]); r[5] = (short)f2bf(b[1]);
    r[6] = (short)f2bf(b[2]); r[7] = (short)f2bf(b[3]);
    return r;
}
static __device__ __forceinline__ bf16x8 scale8v(bf16x8 v, float s) {
    bf16x8 r;
    #pragma unroll
    for (int j = 0; j < 8; ++j) r[j] = (short)f2bf(bf2f(v[j]) * s);
    return r;
}
static __device__ __forceinline__ uint4 cvt8(const float* p) {
    bf16x8 r = cvt8v(p);
    union { bf16x8 v; uint4 u; } c; c.v = r; return c.u;
}
// async global->LDS, 16B/lane; LDS dest = wave-uniform base + lane*16
static __device__ __forceinline__ void glds16(const unsigned short* g, unsigned short* l) {
    __builtin_amdgcn_global_load_lds(
        (const __attribute__((address_space(1))) unsigned int*)g,
        (__attribute__((address_space(3))) unsigned int*)l, 16, 0, 0);
}

// ---------------------------------------------------------------------------
// Fused prep: cvt x -> x_bf, cvt k_g -> kg_bf, transpose+cvt W_qkv, W_out.
// grid 5120: [0,2048) x | [2048,4096) k_g | [4096,4864) Wqkv | [4864,5120) Wout
// ---------------------------------------------------------------------------
static __device__ __forceinline__ void transpose_tile(
    const float* __restrict__ src, unsigned short* __restrict__ dst,
    int R, int C, int bx, int by, int tid)
{
    __shared__ unsigned short t[64 * 72];
    const int r0 = by * 64, c0 = bx * 64;
    #pragma unroll
    for (int i = 0; i < 4; ++i) {
        int idx = tid + i * 256;
        int row = idx >> 4, seg = idx & 15;
        f32x4 v = *(const f32x4*)&src[(size_t)(r0 + row) * C + c0 + seg * 4];
        #pragma unroll
        for (int j = 0; j < 4; ++j) t[row * 72 + seg * 4 + j] = f2bf(v[j]);
    }
    __syncthreads();
    #pragma unroll
    for (int i = 0; i < 2; ++i) {
        int idx = tid + i * 256;
        int row = idx >> 3, seg = idx & 7;
        uint4 tv; unsigned short* tmp = (unsigned short*)&tv;
        #pragma unroll
        for (int j = 0; j < 8; ++j) tmp[j] = t[(seg * 8 + j) * 72 + row];
        *(uint4*)&dst[(size_t)(c0 + row) * R + r0 + seg * 8] = tv;
    }
}

__global__ __launch_bounds__(256) void prep_all(
    const float* __restrict__ x, unsigned short* __restrict__ x_bf,
    const float* __restrict__ kg, unsigned short* __restrict__ kg_bf,
    const float* __restrict__ Wq, unsigned short* __restrict__ wtq,
    const float* __restrict__ Wo, unsigned short* __restrict__ wto)
{
    const int t = blockIdx.x, tid = threadIdx.x;
    if (t < 2048) {
        size_t j = ((size_t)t * 256 + tid) * 8;
        *(uint4*)&x_bf[j] = cvt8(&x[j]);
    } else if (t < 4096) {
        size_t j = ((size_t)(t - 2048) * 256 + tid) * 8;
        *(uint4*)&kg_bf[j] = cvt8(&kg[j]);
    } else if (t < 4864) {
        int tt = t - 4096;               // W_qkv [1024][3072]: 48 col-tiles x 16
        transpose_tile(Wq, wtq, 1024, 3072, tt % 48, tt / 48, tid);
    } else {
        int tt = t - 4864;               // W_out [1024][1024]
        transpose_tile(Wo, wto, 1024, 1024, tt & 15, tt >> 4, tid);
    }
}

// ---------------------------------------------------------------------------
// gemm_qkv: qkv = x_bf @ wtq^T.  Q,K cols (bx<16) -> qk[4096][2048].
// V cols (bx>=16) -> written TRANSPOSED to vt[bh][hd=64][L=2048] via LDS.
// 128x128 tile, BK=32, glds16 staging (m97 pattern).  R0-exact.
// ---------------------------------------------------------------------------
__global__ __launch_bounds__(256) void gemm_qkv(
    const unsigned short* __restrict__ A, const unsigned short* __restrict__ Bt,
    unsigned short* __restrict__ qk, unsigned short* __restrict__ vt)
{
    const int K = 1024;
    __shared__ unsigned short As[128 * 32];
    __shared__ unsigned short Bs[128 * 32];
    __shared__ unsigned short Tb[128 * 136];   // V-transpose scratch
    const int tid = threadIdx.x;
    const int wave = tid >> 6, lane = tid & 63, quad = lane >> 4, l16 = lane & 15;
    const int wr = (wave >> 1) * 64, wc = (wave & 1) * 64;
    const int m0 = blockIdx.y * 128, n0 = blockIdx.x * 128;

    const unsigned short* ga = A  + (size_t)(m0 + wave * 32 + (lane >> 2)) * K + (lane & 3) * 8;
    const unsigned short* gb = Bt + (size_t)(n0 + wave * 32 + (lane >> 2)) * K + (lane & 3) * 8;
    unsigned short* la = &As[wave * 32 * 32];
    unsigned short* lb = &Bs[wave * 32 * 32];
    const size_t step16 = (size_t)16 * K;

    f32x4 acc[4][4];
    #pragma unroll
    for (int i = 0; i < 4; ++i)
        #pragma unroll
        for (int j = 0; j < 4; ++j) acc[i][j] = (f32x4){0.f, 0.f, 0.f, 0.f};

    for (int kt = 0; kt < K; kt += 32) {
        glds16(ga, la); glds16(ga + step16, la + 512);
        glds16(gb, lb); glds16(gb + step16, lb + 512);
        ga += 32; gb += 32;
        __syncthreads();
        bf16x8 af[4], bf[4];
        #pragma unroll
        for (int i = 0; i < 4; ++i) {
            af[i] = *(const bf16x8*)&As[(wr + i * 16 + l16) * 32 + quad * 8];
            bf[i] = *(const bf16x8*)&Bs[(wc + i * 16 + l16) * 32 + quad * 8];
        }
        #pragma unroll
        for (int mi = 0; mi < 4; ++mi)
            #pragma unroll
            for (int ni = 0; ni < 4; ++ni)
                acc[mi][ni] = __builtin_amdgcn_mfma_f32_16x16x32_bf16(
                    af[mi], bf[ni], acc[mi][ni], 0, 0, 0);
        __syncthreads();
    }

    if (blockIdx.x < 16) {        // Q|K part: normal write, stride 2048
        #pragma unroll
        for (int mi = 0; mi < 4; ++mi)
            #pragma unroll
            for (int ni = 0; ni < 4; ++ni)
                #pragma unroll
                for (int r = 0; r < 4; ++r) {
                    int row = m0 + wr + mi * 16 + quad * 4 + r;
                    int col = n0 + wc + ni * 16 + l16;
                    qk[(size_t)row * 2048 + col] = f2bf(acc[mi][ni][r]);
                }
    } else {                      // V part: transpose via LDS -> vt[bh][hd][L]
        __syncthreads();
        #pragma unroll
        for (int mi = 0; mi < 4; ++mi)
            #pragma unroll
            for (int ni = 0; ni < 4; ++ni)
                #pragma unroll
                for (int r = 0; r < 4; ++r) {
                    int col = wc + ni * 16 + l16;            // hd-ish (0..127)
                    int row = wr + mi * 16 + quad * 4 + r;   // pos (0..127)
                    Tb[col * 136 + row] = f2bf(acc[mi][ni][r]);
                }
        __syncthreads();
        const int col = tid >> 1, r0 = (tid & 1) * 64;
        const int bh = (m0 >> 11) * 16 + ((int)blockIdx.x - 16) * 2 + (col >> 6);
        size_t base = ((size_t)bh * 64 + (col & 63)) * 2048 + (m0 & 2047) + r0;
        #pragma unroll
        for (int k = 0; k < 8; ++k)
            *(uint4*)&vt[base + k * 8] = *(const uint4*)&Tb[col * 136 + r0 + k * 8];
    }
}

// ---------------------------------------------------------------------------
// gemm2: out = y_ws @ wto^T, f32 out.  128(M) x 64(N) tile -> 512 blocks.
// 4 waves: 2x2, each 64x32.  R0-exact.
// ---------------------------------------------------------------------------
__global__ __launch_bounds__(256) void gemm_n64(
    const unsigned short* __restrict__ A, const unsigned short* __restrict__ Bt,
    float* __restrict__ C)
{
    const int K = 1024, N = 1024;
    __shared__ unsigned short As[128 * 32];
    __shared__ unsigned short Bs[64 * 32];
    const int tid = threadIdx.x;
    const int wave = tid >> 6, lane = tid & 63, quad = lane >> 4, l16 = lane & 15;
    const int wr = (wave >> 1) * 64, wc = (wave & 1) * 32;
    const int m0 = blockIdx.y * 128, n0 = blockIdx.x * 64;

    const unsigned short* ga = A  + (size_t)(m0 + wave * 32 + (lane >> 2)) * K + (lane & 3) * 8;
    const unsigned short* gb = Bt + (size_t)(n0 + wave * 16 + (lane >> 2)) * K + (lane & 3) * 8;
    unsigned short* la = &As[wave * 32 * 32];
    unsigned short* lb = &Bs[wave * 16 * 32];
    const size_t step16 = (size_t)16 * K;

    f32x4 acc[4][2];
    #pragma unroll
    for (int i = 0; i < 4; ++i)
        #pragma unroll
        for (int j = 0; j < 2; ++j) acc[i][j] = (f32x4){0.f, 0.f, 0.f, 0.f};

    for (int kt = 0; kt < K; kt += 32) {
        glds16(ga, la); glds16(ga + step16, la + 512);
        glds16(gb, lb);
        ga += 32; gb += 32;
        __syncthreads();
        bf16x8 af[4], bf[2];
        #pragma unroll
        for (int i = 0; i < 4; ++i)
            af[i] = *(const bf16x8*)&As[(wr + i * 16 + l16) * 32 + quad * 8];
        #pragma unroll
        for (int i = 0; i < 2; ++i)
            bf[i] = *(const bf16x8*)&Bs[(wc + i * 16 + l16) * 32 + quad * 8];
        #pragma unroll
        for (int mi = 0; mi < 4; ++mi)
            #pragma unroll
            for (int ni = 0; ni < 2; ++ni)
                acc[mi][ni] = __builtin_amdgcn_mfma_f32_16x16x32_bf16(
                    af[mi], bf[ni], acc[mi][ni], 0, 0, 0);
        __syncthreads();
    }
    #pragma unroll
    for (int mi = 0; mi < 4; ++mi)
        #pragma unroll
        for (int ni = 0; ni < 2; ++ni)
            #pragma unroll
            for (int r = 0; r < 4; ++r) {
                int row = m0 + wr + mi * 16 + quad * 4 + r;
                int col = n0 + wc + ni * 16 + l16;
                C[(size_t)row * N + col] = acc[mi][ni][r];
            }
}

// ---------------------------------------------------------------------------
// attn13 = attn7 body + KEY-DIMENSION SPLIT for long blocks.
// Fixed-base softmax (no running max) => partial (o, lsum) over disjoint key
// ranges ADD exactly.  qt>=16 is computed by TWO blocks: half0 = tiles
// [0,ht), half1 = tiles [ht,qt] + diagonal, ht=(qt+1)/2.  Max serial chain
// drops 32 -> 17 tiles (the measured critical path: 60us ~= 32 x 1.9us).
// Split blocks write f32 partial o + lsum; attn_combine reduces.
// Per-block body is attn7-exact: same LDS (32 KiB, 5 blk/CU), swizzles, VGPR.
// Grid 32 x 48 = 1536 blocks, heavy-first.
// ---------------------------------------------------------------------------
__global__ __launch_bounds__(256, 5) void attn13(
    const unsigned short* __restrict__ qk, const float* __restrict__ qg,
    const unsigned short* __restrict__ kgb, const unsigned short* __restrict__ vt,
    unsigned short* __restrict__ y,
    float* __restrict__ po0, float* __restrict__ po1,
    float* __restrict__ ls0, float* __restrict__ ls1)
{
    const int L = 2048, DS = 2048, Dm = 1024;
    const float SC2 = 0.125f * 1.44269504088896f / 7.6246189861593985f;

    // role map (heavy-first): y<16: half1 qt=31-y | y<32: half0 qt=47-y |
    // y>=32: unsplit qt=47-y (15..0)
    const int yb = (int)blockIdx.y;
    const bool isH1 = (yb < 16);
    const bool isSplit = (yb < 32);
    const int qt = isH1 ? (31 - yb) : (47 - yb);
    const int ht = (qt + 1) >> 1;
    const int nfull = isSplit ? (isH1 ? qt - ht : ht) : qt;
    const bool dodiag = !isSplit || isH1;
    const int kt0 = (isSplit && isH1) ? ht : 0;

    const int bh = blockIdx.x, b = bh >> 4, h = bh & 15;
    const int tid = threadIdx.x, wave = tid >> 6, lane = tid & 63;
    const int quad = lane >> 4, l16 = lane & 15;

    __shared__ unsigned short K_l[4096];     // [64][64] swizzled
    __shared__ unsigned short G_l[4096];
    __shared__ unsigned short V_l[4096];     // [hd][key] swizzled
    __shared__ unsigned short P_l[4096];     // per-wave [16][64] swizzled
    unsigned short* Pw = &P_l[wave * 1024];

    bf16x8 qf[2], gf[2];
    {
        const int qrow = qt * 64 + wave * 16 + l16;
        const unsigned short* qp = qk + (size_t)(b * L + qrow) * DS + h * 64;
        const float* gp = qg + (size_t)(b * L + qrow) * Dm + h * 64;
        #pragma unroll
        for (int c = 0; c < 2; ++c) {
            qf[c] = scale8v(*(const bf16x8*)(qp + c * 32 + quad * 8), SC2);
            gf[c] = scale8v(cvt8v(gp + c * 32 + quad * 8), SC2);
        }
    }

    f32x4 o[4];
    #pragma unroll
    for (int nd = 0; nd < 4; ++nd) o[nd] = (f32x4){0.f, 0.f, 0.f, 0.f};
    float lsum = 0.f;

    const int srow = wave * 16 + (lane >> 3);
    const int c8 = (((lane & 7) ^ (lane >> 3)) & 7) * 8;
    const unsigned short* pk = qk + (size_t)(b * L + kt0 * 64 + srow) * DS + 1024 + h * 64 + c8;
    const unsigned short* pg = kgb + (size_t)(b * L + kt0 * 64 + srow) * Dm + h * 64 + c8;
    const unsigned short* pv = vt + ((size_t)bh * 64 + srow) * L + kt0 * 64 + c8;
    unsigned short* lK = &K_l[wave * 1024];
    unsigned short* lG = &G_l[wave * 1024];
    unsigned short* lV = &V_l[wave * 1024];

    const int rb = l16 * 128;
    const int swz0 = ((quad     ^ (l16 & 7)) * 16);
    const int swz1 = (((4 + quad) ^ (l16 & 7)) * 16);
    // P write: short idx l16*64 + ((ni*2+(quad>>1))^(l16&7))*8 + (quad&1)*4
    const int pwb = l16 * 64 + (quad & 1) * 4;
    const int pwc = quad >> 1, pxr = l16 & 7;

    for (int kt = 0; kt < nfull; ++kt) {
        __syncthreads();
        glds16(pk, lK); glds16(pk + 8 * DS, lK + 512);
        glds16(pg, lG); glds16(pg + 8 * Dm, lG + 512);
        glds16(pv, lV); glds16(pv + 8 * L,  lV + 512);
        pk += 64 * DS; pg += 64 * Dm; pv += 64;
        __syncthreads();

        #pragma unroll
        for (int ni = 0; ni < 4; ++ni) {
            bf16x8 kf0 = *(const bf16x8*)((const char*)K_l + rb + swz0 + ni * 2048);
            bf16x8 kf1 = *(const bf16x8*)((const char*)K_l + rb + swz1 + ni * 2048);
            bf16x8 gb0 = *(const bf16x8*)((const char*)G_l + rb + swz0 + ni * 2048);
            bf16x8 gb1 = *(const bf16x8*)((const char*)G_l + rb + swz1 + ni * 2048);
            f32x4 a = (f32x4){0.f, 0.f, 0.f, 0.f};
            a = __builtin_amdgcn_mfma_f32_16x16x32_bf16(kf0, qf[0], a, 0, 0, 0);
            a = __builtin_amdgcn_mfma_f32_16x16x32_bf16(gb0, gf[0], a, 0, 0, 0);
            a = __builtin_amdgcn_mfma_f32_16x16x32_bf16(kf1, qf[1], a, 0, 0, 0);
            a = __builtin_amdgcn_mfma_f32_16x16x32_bf16(gb1, gf[1], a, 0, 0, 0);
            float e0 = exp2f(a[0]), e1 = exp2f(a[1]);
            float e2 = exp2f(a[2]), e3 = exp2f(a[3]);
            lsum += (e0 + e1) + (e2 + e3);
            unsigned int p01 = pack2bf(e0, e1), p23 = pack2bf(e2, e3);
            *(unsigned long long*)&Pw[pwb + (((ni * 2 + pwc) ^ pxr) * 8)] =
                ((unsigned long long)p23 << 32) | p01;
        }
        asm volatile("s_waitcnt lgkmcnt(0)" ::: "memory");

        bf16x8 pa[2];
        #pragma unroll
        for (int c = 0; c < 2; ++c)
            pa[c] = *(const bf16x8*)&Pw[l16 * 64 + (((c * 4 + quad) ^ pxr) * 8)];
        #pragma unroll
        for (int nd = 0; nd < 4; ++nd) {
            bf16x8 vf0 = *(const bf16x8*)((const char*)V_l + rb + swz0 + nd * 2048);
            bf16x8 vf1 = *(const bf16x8*)((const char*)V_l + rb + swz1 + nd * 2048);
            o[nd] = __builtin_amdgcn_mfma_f32_16x16x32_bf16(pa[0], vf0, o[nd], 0, 0, 0);
            o[nd] = __builtin_amdgcn_mfma_f32_16x16x32_bf16(pa[1], vf1, o[nd], 0, 0, 0);
        }
    }

    // ---- diagonal tile kt == qt (only unsplit or half1) ----
    if (dodiag) {
        __syncthreads();
        glds16(pk, lK); glds16(pk + 8 * DS, lK + 512);
        glds16(pg, lG); glds16(pg + 8 * Dm, lG + 512);
        glds16(pv, lV); glds16(pv + 8 * L,  lV + 512);
        __syncthreads();

        #pragma unroll
        for (int ni = 0; ni < 4; ++ni) {
            if (ni > wave) {
                *(unsigned long long*)&Pw[pwb + (((ni * 2 + pwc) ^ pxr) * 8)] = 0ull;
                continue;
            }
            bf16x8 kf0 = *(const bf16x8*)((const char*)K_l + rb + swz0 + ni * 2048);
            bf16x8 kf1 = *(const bf16x8*)((const char*)K_l + rb + swz1 + ni * 2048);
            bf16x8 gb0 = *(const bf16x8*)((const char*)G_l + rb + swz0 + ni * 2048);
            bf16x8 gb1 = *(const bf16x8*)((const char*)G_l + rb + swz1 + ni * 2048);
            f32x4 a = (f32x4){0.f, 0.f, 0.f, 0.f};
            a = __builtin_amdgcn_mfma_f32_16x16x32_bf16(kf0, qf[0], a, 0, 0, 0);
            a = __builtin_amdgcn_mfma_f32_16x16x32_bf16(gb0, gf[0], a, 0, 0, 0);
            a = __builtin_amdgcn_mfma_f32_16x16x32_bf16(kf1, qf[1], a, 0, 0, 0);
            a = __builtin_amdgcn_mfma_f32_16x16x32_bf16(gb1, gf[1], a, 0, 0, 0);
            float e0, e1, e2, e3;
            if (ni < wave) {
                e0 = exp2f(a[0]); e1 = exp2f(a[1]);
                e2 = exp2f(a[2]); e3 = exp2f(a[3]);
            } else {
                e0 = (quad * 4 + 0 <= l16) ? exp2f(a[0]) : 0.f;
                e1 = (quad * 4 + 1 <= l16) ? exp2f(a[1]) : 0.f;
                e2 = (quad * 4 + 2 <= l16) ? exp2f(a[2]) : 0.f;
                e3 = (quad * 4 + 3 <= l16) ? exp2f(a[3]) : 0.f;
            }
            lsum += (e0 + e1) + (e2 + e3);
            unsigned int p01 = pack2bf(e0, e1), p23 = pack2bf(e2, e3);
            *(unsigned long long*)&Pw[pwb + (((ni * 2 + pwc) ^ pxr) * 8)] =
                ((unsigned long long)p23 << 32) | p01;
        }
        asm volatile("s_waitcnt lgkmcnt(0)" ::: "memory");

        bf16x8 pa[2];
        #pragma unroll
        for (int c = 0; c < 2; ++c)
            pa[c] = *(const bf16x8*)&Pw[l16 * 64 + (((c * 4 + quad) ^ pxr) * 8)];
        #pragma unroll
        for (int nd = 0; nd < 4; ++nd) {
            bf16x8 vf0 = *(const bf16x8*)((const char*)V_l + rb + swz0 + nd * 2048);
            bf16x8 vf1 = *(const bf16x8*)((const char*)V_l + rb + swz1 + nd * 2048);
            o[nd] = __builtin_amdgcn_mfma_f32_16x16x32_bf16(pa[0], vf0, o[nd], 0, 0, 0);
            o[nd] = __builtin_amdgcn_mfma_f32_16x16x32_bf16(pa[1], vf1, o[nd], 0, 0, 0);
        }
    }

    float rs = lsum;
    rs += __shfl_xor(rs, 16);
    rs += __shfl_xor(rs, 32);

    if (isSplit) {
        // partial store: o (f32) + row sums; combine kernel finishes
        const int pair = bh * 16 + (qt - 16);
        float* po = (isH1 ? po1 : po0) + (size_t)pair * 4096;
        float* pls = (isH1 ? ls1 : ls0) + (size_t)pair * 64;
        #pragma unroll
        for (int r = 0; r < 4; ++r) {
            int row = wave * 16 + quad * 4 + r;
            #pragma unroll
            for (int nd = 0; nd < 4; ++nd)
                po[row * 64 + nd * 16 + l16] = o[nd][r];
        }
        if (lane < 16) pls[wave * 16 + lane] = rs;   // rs at quad==0: row l16=lane
    } else {
        #pragma unroll
        for (int r = 0; r < 4; ++r) {
            float inv = 1.f / __shfl(rs, (lane & 48) | (quad * 4 + r));
            int row = qt * 64 + wave * 16 + quad * 4 + r;
            #pragma unroll
            for (int nd = 0; nd < 4; ++nd)
                y[(size_t)(b * L + row) * Dm + h * 64 + nd * 16 + l16] =
                    f2bf(o[nd][r] * inv);
        }
    }
}

// ---------------------------------------------------------------------------
// combine: y = (po0 + po1) / (ls0 + ls1) for split row-groups (qt >= 16).
// 512 blocks x 256 threads; ~20 MB traffic ~= 3.5 us.
// ---------------------------------------------------------------------------
__global__ __launch_bounds__(256) void attn_combine(
    const float* __restrict__ po0, const float* __restrict__ po1,
    const float* __restrict__ ls0, const float* __restrict__ ls1,
    unsigned short* __restrict__ y)
{
    const int pair = blockIdx.x;                 // 512
    const int bh = pair >> 4, qt = (pair & 15) + 16;
    const int b = bh >> 4, h = bh & 15;
    const int tid = threadIdx.x;
    const int r = tid >> 2, c0 = (tid & 3) * 16; // 64 rows x 4 chunks of 16

    __shared__ float inv[64];
    if (tid < 64) inv[tid] = 1.f / (ls0[pair * 64 + tid] + ls1[pair * 64 + tid]);
    __syncthreads();

    const float* p0 = po0 + (size_t)pair * 4096 + r * 64 + c0;
    const float* p1 = po1 + (size_t)pair * 4096 + r * 64 + c0;
    unsigned short* yp = y + (size_t)(b * 2048 + qt * 64 + r) * 1024 + h * 64 + c0;
    const float s = inv[r];
    #pragma unroll
    for (int j = 0; j < 4; ++j) {
        f32x4 a = *(const f32x4*)(p0 + j * 4);
        f32x4 c = *(const f32x4*)(p1 + j * 4);
        yp[j * 4 + 0] = f2bf((a[0] + c[0]) * s);
        yp[j * 4 + 1] = f2bf((a[1] + c[1]) * s);
        yp[j * 4 + 2] = f2bf((a[2] + c[2]) * s);
        yp[j * 4 + 3] = f2bf((a[3] + c[3]) * s);
    }
}

// ---------------------------------------------------------------------------
extern "C" void kernel_launch(void* const* d_in, const int* in_sizes, int n_in,
                              void* d_out, int out_size, void* d_ws, size_t ws_size,
                              hipStream_t stream) {
    const float* x     = (const float*)d_in[0];
    const float* q_g   = (const float*)d_in[1];
    const float* k_g   = (const float*)d_in[2];
    const float* W_qkv = (const float*)d_in[3];
    const float* W_out = (const float*)d_in[4];
    float* out = (float*)d_out;
    unsigned short* ws = (unsigned short*)d_ws;

    unsigned short* qk_ws = ws;                  // [4096][2048]  Q|K
    unsigned short* y_ws  = ws + 8388608;        // [4096][1024]
    unsigned short* wtq   = ws + 12582912;       // [3072][1024]  (dead after gemm_qkv)
    unsigned short* kg_bf = ws + 16777216;       // [4096][1024]
    unsigned short* x_bf  = ws + 20971520;       // [4096][1024]  (dead after gemm_qkv)
    unsigned short* vt_bf = ws + 25165824;       // [32][64][2048]
    unsigned short* wto   = ws + 29360128;       // [1024][1024]  (moved: alive for gemm_n64)
    // split-attention partials (temporal reuse of dead regions):
    float* po0 = (float*)(ws + 20971520);        // 8 MB over x_bf
    float* po1 = (float*)(ws + 12582912);        // 8 MB over wtq (+old wto slot)
    float* ls0 = (float*)(ws + 30408704);        // 128 KB
    float* ls1 = (float*)(ws + 30474240);        // 128 KB  (end: 30539776 shorts)

    dim3 blk(256);
    prep_all<<<5120, blk, 0, stream>>>(x, x_bf, k_g, kg_bf, W_qkv, wtq, W_out, wto);
    gemm_qkv<<<dim3(24, 32), blk, 0, stream>>>(x_bf, wtq, qk_ws, vt_bf);
    attn13<<<dim3(32, 48), blk, 0, stream>>>(qk_ws, q_g, kg_bf, vt_bf, y_ws,
                                             po0, po1, ls0, ls1);
    attn_combine<<<512, blk, 0, stream>>>(po0, po1, ls0, ls1, y_ws);
    gemm_n64<<<dim3(16, 32), blk, 0, stream>>>(y_ws, wto, out);
}